// Round 2
// baseline (1191.983 us; speedup 1.0000x reference)
//
#include <hip/hip_runtime.h>

#define HW   3136
#define NCH  64
#define CRED 32
#define NB   8
#define EPSV 1e-5f
#define QSPLIT 8
#define QCH    14

#define K2_T  448   // 7 waves; 448*7 = 3136
#define K2_IT 7
#define K2_R  8     // rows of R per block

// ---------------- K1: conv1x1 + BN1 + ReLU6 -> Gt[n][p][i] (fp32, transposed) ----
__global__ __launch_bounds__(256) void k1_conv1x1(
    const float* __restrict__ l, const float* __restrict__ w,
    const float* __restrict__ gamma, const float* __restrict__ beta,
    const float* __restrict__ mean, const float* __restrict__ var,
    float* __restrict__ Gt)
{
    __shared__ float Wt[NCH][NCH];  // Wt[c][i]
    __shared__ float Lt[NCH][64];   // Lt[c][j]
    const int t  = threadIdx.x;
    const int n  = blockIdx.y;
    const int p0 = blockIdx.x * 64;

    for (int idx = t; idx < NCH * 64; idx += 256) {
        int c = idx >> 6, i = idx & 63;
        Wt[c][i] = w[i * NCH + c];
        Lt[c][i] = l[((size_t)n * NCH + c) * HW + p0 + i];
    }
    __syncthreads();

    const int i   = t & 63;
    const int pj0 = t >> 6;            // 0..3
    const float mu = mean[i];
    const float sc = rsqrtf(var[i] + EPSV) * gamma[i];
    const float bi = beta[i];

    float acc[16];
#pragma unroll
    for (int k = 0; k < 16; ++k) acc[k] = 0.f;
#pragma unroll
    for (int c = 0; c < NCH; ++c) {
        float wci = Wt[c][i];
#pragma unroll
        for (int k = 0; k < 16; ++k) acc[k] += wci * Lt[c][pj0 + 4 * k];
    }
#pragma unroll
    for (int k = 0; k < 16; ++k) {
        float y = (acc[k] - mu) * sc + bi;
        y = fminf(fmaxf(y, 0.f), 6.f);
        Gt[((size_t)n * HW + p0 + pj0 + 4 * k) * NCH + i] = y;
    }
}

// ------- K2: R = rowsoftmax(theta^T theta), 8 rows per block, S kept in regs ----
__global__ __launch_bounds__(K2_T) void k2_rowsoftmax(
    const float* __restrict__ l, float* __restrict__ R, int n0)
{
    __shared__ float tq[K2_R][CRED];
    __shared__ float red[8][K2_R];

    const int t = threadIdx.x;
    const int n = n0 + blockIdx.y;
    const size_t Roff = (size_t)blockIdx.y * HW * HW;
    const int q0 = blockIdx.x * K2_R;

    for (int idx = t; idx < K2_R * CRED; idx += K2_T) {
        int r = idx >> 5, c = idx & 31;
        tq[r][c] = l[((size_t)n * NCH + c) * HW + q0 + r];
    }
    __syncthreads();

    float s[K2_IT][K2_R];
#pragma unroll
    for (int k = 0; k < K2_IT; ++k)
#pragma unroll
        for (int r = 0; r < K2_R; ++r) s[k][r] = 0.f;

    for (int c = 0; c < CRED; ++c) {
        float tqc[K2_R];
#pragma unroll
        for (int r = 0; r < K2_R; ++r) tqc[r] = tq[r][c];
#pragma unroll
        for (int k = 0; k < K2_IT; ++k) {
            float th = l[((size_t)n * NCH + c) * HW + t + k * K2_T];
#pragma unroll
            for (int r = 0; r < K2_R; ++r) s[k][r] += tqc[r] * th;
        }
    }

    float pmax[K2_R];
#pragma unroll
    for (int r = 0; r < K2_R; ++r) pmax[r] = -1e30f;
#pragma unroll
    for (int k = 0; k < K2_IT; ++k)
#pragma unroll
        for (int r = 0; r < K2_R; ++r) pmax[r] = fmaxf(pmax[r], s[k][r]);

    const int lane = t & 63, wid = t >> 6;
#pragma unroll
    for (int r = 0; r < K2_R; ++r) {
        float v = pmax[r];
        for (int off = 32; off > 0; off >>= 1) v = fmaxf(v, __shfl_xor(v, off, 64));
        if (lane == 0) red[wid][r] = v;
    }
    __syncthreads();
    float m[K2_R];
#pragma unroll
    for (int r = 0; r < K2_R; ++r) {
        float v = red[0][r];
#pragma unroll
        for (int wv = 1; wv < 7; ++wv) v = fmaxf(v, red[wv][r]);
        m[r] = v;
    }
    __syncthreads();

    float ps[K2_R];
#pragma unroll
    for (int r = 0; r < K2_R; ++r) ps[r] = 0.f;
#pragma unroll
    for (int k = 0; k < K2_IT; ++k)
#pragma unroll
        for (int r = 0; r < K2_R; ++r) {
            s[k][r] = __expf(s[k][r] - m[r]);
            ps[r] += s[k][r];
        }

#pragma unroll
    for (int r = 0; r < K2_R; ++r) {
        float v = ps[r];
        for (int off = 32; off > 0; off >>= 1) v += __shfl_xor(v, off, 64);
        if (lane == 0) red[wid][r] = v;
    }
    __syncthreads();
    float inv[K2_R];
#pragma unroll
    for (int r = 0; r < K2_R; ++r) {
        float v = 0.f;
#pragma unroll
        for (int wv = 0; wv < 7; ++wv) v += red[wv][r];
        inv[r] = 1.f / v;
    }

#pragma unroll
    for (int k = 0; k < K2_IT; ++k)
#pragma unroll
        for (int r = 0; r < K2_R; ++r)
            R[Roff + (size_t)(q0 + r) * HW + t + k * K2_T] = s[k][r] * inv[r];
}

// ---- K3a: partial Out_unnorm and Z over a q-slice:  acc[i] += exp(R[q,p])*G[i,q]
__global__ __launch_bounds__(128) void k3a_partial(
    const float* __restrict__ R, const float* __restrict__ Gt,
    float* __restrict__ Part, float* __restrict__ Zpart, int n0)
{
    __shared__ float gl[QCH][NCH];
    const int t  = threadIdx.x;
    const int p  = (blockIdx.x << 6) + (t & 63);
    const int g  = t >> 6;  // 0 or 1 -> i in [g*32, g*32+32)
    const int qs = blockIdx.y;
    const int nb = blockIdx.z;
    const int n  = n0 + nb;

    const float* Rn = R  + (size_t)nb * HW * HW;
    const float* Gn = Gt + (size_t)n * HW * NCH;

    float acc[32];
#pragma unroll
    for (int j = 0; j < 32; ++j) acc[j] = 0.f;
    float z = 0.f;

    const int qbase = qs * (HW / QSPLIT);  // 392 q's per slice
    for (int ch = 0; ch < (HW / QSPLIT) / QCH; ++ch) {  // 28 chunks
        __syncthreads();
        for (int idx = t; idx < QCH * NCH; idx += 128)
            gl[idx >> 6][idx & 63] =
                Gn[(size_t)(qbase + ch * QCH + (idx >> 6)) * NCH + (idx & 63)];
        __syncthreads();
#pragma unroll
        for (int qq = 0; qq < QCH; ++qq) {
            int q = qbase + ch * QCH + qq;
            float e = __expf(Rn[(size_t)q * HW + p]);
            z += e;
#pragma unroll
            for (int j = 0; j < 32; ++j) acc[j] += e * gl[qq][(g << 5) + j];
        }
    }

    float* Pn = Part + ((size_t)nb * QSPLIT + qs) * ((size_t)NCH * HW);
#pragma unroll
    for (int j = 0; j < 32; ++j)
        Pn[(size_t)((g << 5) + j) * HW + p] = acc[j];
    if (g == 0) Zpart[((size_t)nb * QSPLIT + qs) * HW + p] = z;
}

// ---- K3b: reduce q-slices, divide by Z -> OutPre[n][i][p] ----------------------
__global__ __launch_bounds__(256) void k3b_reduce(
    const float* __restrict__ Part, const float* __restrict__ Zpart,
    float* __restrict__ OutPre, int n0)
{
    const int t  = threadIdx.x;
    const int p  = blockIdx.x * 256 + t;
    const int ic = blockIdx.y;
    const int nb = blockIdx.z;
    if (p >= HW) return;

    const float* Zn = Zpart + (size_t)nb * QSPLIT * HW;
    float zt = 0.f;
#pragma unroll
    for (int qs = 0; qs < QSPLIT; ++qs) zt += Zn[(size_t)qs * HW + p];
    const float zi = 1.f / zt;

    const float* Pn = Part + (size_t)nb * QSPLIT * NCH * HW;
    float* On = OutPre + (size_t)(n0 + nb) * NCH * HW;
#pragma unroll
    for (int j = 0; j < 8; ++j) {
        int i = ic * 8 + j;
        float sa = 0.f;
#pragma unroll
        for (int qs = 0; qs < QSPLIT; ++qs)
            sa += Pn[((size_t)qs * NCH + i) * HW + p];
        On[(size_t)i * HW + p] = sa * zi;
    }
}

// ---- K4: depthwise 3x3 (pad 1) + BN2 + residual -> fp32 out --------------------
__global__ __launch_bounds__(256) void k4_dwconv(
    const float* __restrict__ OutPre, const float* __restrict__ l,
    const float* __restrict__ wdw,
    const float* __restrict__ gamma, const float* __restrict__ beta,
    const float* __restrict__ mean, const float* __restrict__ var,
    float* __restrict__ out)
{
    const size_t e = (size_t)blockIdx.x * 256 + threadIdx.x;
    if (e >= (size_t)NB * NCH * HW) return;
    const int p = (int)(e % HW);
    const int i = (int)((e / HW) % NCH);
    const int y = p / 56, x = p % 56;
    const float* src = OutPre + (e - p);

    float acc = 0.f;
#pragma unroll
    for (int dy = -1; dy <= 1; ++dy) {
        int yy = y + dy;
        if (yy < 0 || yy >= 56) continue;
#pragma unroll
        for (int dx = -1; dx <= 1; ++dx) {
            int xx = x + dx;
            if (xx < 0 || xx >= 56) continue;
            acc += wdw[i * 9 + (dy + 1) * 3 + (dx + 1)] * src[yy * 56 + xx];
        }
    }
    const float sc = rsqrtf(var[i] + EPSV) * gamma[i];
    float yv = (acc - mean[i]) * sc + beta[i];
    yv += l[e];
    out[e] = yv;
}

// -------------------------------------------------------------------------------
extern "C" void kernel_launch(void* const* d_in, const int* in_sizes, int n_in,
                              void* d_out, int out_size, void* d_ws, size_t ws_size,
                              hipStream_t stream)
{
    const float* l      = (const float*)d_in[0];
    const float* w_in   = (const float*)d_in[1];
    const float* gamma1 = (const float*)d_in[2];
    const float* beta1  = (const float*)d_in[3];
    const float* mean1  = (const float*)d_in[4];
    const float* var1   = (const float*)d_in[5];
    const float* w_dw   = (const float*)d_in[6];
    const float* gamma2 = (const float*)d_in[7];
    const float* beta2  = (const float*)d_in[8];
    const float* mean2  = (const float*)d_in[9];
    const float* var2   = (const float*)d_in[10];
    float* out = (float*)d_out;

    char* ws = (char*)d_ws;
    const size_t szGt   = (size_t)NB * HW * NCH * 4;
    const size_t szOut  = szGt;
    const size_t szZ    = (size_t)NB * QSPLIT * HW * 4;
    const size_t szR1   = (size_t)HW * HW * 4;
    const size_t szRall = szR1 * NB;
    const size_t szP1   = (size_t)QSPLIT * NCH * HW * 4;
    const size_t szPall = szP1 * NB;

    float* Gt     = (float*)ws;
    float* OutPre = (float*)(ws + szGt);
    float* Zp     = (float*)(ws + szGt + szOut);
    float* R      = (float*)(ws + szGt + szOut + szZ);
    const bool allN = ws_size >= szGt + szOut + szZ + szRall + szPall;
    float* Part   = (float*)(ws + szGt + szOut + szZ + (allN ? szRall : szR1));

    k1_conv1x1<<<dim3(HW / 64, NB), 256, 0, stream>>>(
        l, w_in, gamma1, beta1, mean1, var1, Gt);

    if (allN) {
        k2_rowsoftmax<<<dim3(HW / K2_R, NB), K2_T, 0, stream>>>(l, R, 0);
        k3a_partial<<<dim3(HW / 64, QSPLIT, NB), 128, 0, stream>>>(R, Gt, Part, Zp, 0);
        k3b_reduce<<<dim3((HW + 255) / 256, 8, NB), 256, 0, stream>>>(Part, Zp, OutPre, 0);
    } else {
        for (int n = 0; n < NB; ++n) {
            k2_rowsoftmax<<<dim3(HW / K2_R, 1), K2_T, 0, stream>>>(l, R, n);
            k3a_partial<<<dim3(HW / 64, QSPLIT, 1), 128, 0, stream>>>(R, Gt, Part, Zp, n);
            k3b_reduce<<<dim3((HW + 255) / 256, 8, 1), 256, 0, stream>>>(Part, Zp, OutPre, n);
        }
    }

    k4_dwconv<<<dim3((NB * NCH * HW + 255) / 256), 256, 0, stream>>>(
        OutPre, l, w_dw, gamma2, beta2, mean2, var2, out);
}

// Round 3
// 438.153 us; speedup vs baseline: 2.7205x; 2.7205x over previous
//
#include <hip/hip_runtime.h>

#define HW   3136
#define NCH  64
#define CRED 32
#define NB   8
#define EPSV 1e-5f

#define QS2  7          // q-splits in k3f
#define QPB  (HW / QS2) // 448 q per block
#define QT   64         // q tile
#define NT   (QPB / QT) // 7 tiles per block

#define K2_T  448
#define K2_IT 7
#define K2_R  8

// ---------------- K1: conv1x1 + BN1 + ReLU6 -> Gt[n][p][i] (fp32, transposed) ----
__global__ __launch_bounds__(256) void k1_conv1x1(
    const float* __restrict__ l, const float* __restrict__ w,
    const float* __restrict__ gamma, const float* __restrict__ beta,
    const float* __restrict__ mean, const float* __restrict__ var,
    float* __restrict__ Gt)
{
    __shared__ float Wt[NCH][NCH];
    __shared__ float Lt[NCH][64];
    const int t  = threadIdx.x;
    const int n  = blockIdx.y;
    const int p0 = blockIdx.x * 64;

    for (int idx = t; idx < NCH * 64; idx += 256) {
        int c = idx >> 6, i = idx & 63;
        Wt[c][i] = w[i * NCH + c];
        Lt[c][i] = l[((size_t)n * NCH + c) * HW + p0 + i];
    }
    __syncthreads();

    const int i   = t & 63;
    const int pj0 = t >> 6;
    const float mu = mean[i];
    const float sc = rsqrtf(var[i] + EPSV) * gamma[i];
    const float bi = beta[i];

    float acc[16];
#pragma unroll
    for (int k = 0; k < 16; ++k) acc[k] = 0.f;
#pragma unroll
    for (int c = 0; c < NCH; ++c) {
        float wci = Wt[c][i];
#pragma unroll
        for (int k = 0; k < 16; ++k) acc[k] += wci * Lt[c][pj0 + 4 * k];
    }
#pragma unroll
    for (int k = 0; k < 16; ++k) {
        float y = (acc[k] - mu) * sc + bi;
        y = fminf(fmaxf(y, 0.f), 6.f);
        Gt[((size_t)n * HW + p0 + pj0 + 4 * k) * NCH + i] = y;
    }
}

// ------- K2s: row stats of rowsoftmax(theta^T theta): m_q and 1/Z_q --------------
__global__ __launch_bounds__(K2_T) void k2s_stats(
    const float* __restrict__ l, float* __restrict__ mrow, float* __restrict__ zrow)
{
    __shared__ float tq[K2_R][CRED];
    __shared__ float red[8][K2_R];

    const int t = threadIdx.x;
    const int n = blockIdx.y;
    const int q0 = blockIdx.x * K2_R;

    for (int idx = t; idx < K2_R * CRED; idx += K2_T) {
        int r = idx >> 5, c = idx & 31;
        tq[r][c] = l[((size_t)n * NCH + c) * HW + q0 + r];
    }
    __syncthreads();

    float s[K2_IT][K2_R];
#pragma unroll
    for (int k = 0; k < K2_IT; ++k)
#pragma unroll
        for (int r = 0; r < K2_R; ++r) s[k][r] = 0.f;

    for (int c = 0; c < CRED; ++c) {
        float tqc[K2_R];
#pragma unroll
        for (int r = 0; r < K2_R; ++r) tqc[r] = tq[r][c];
#pragma unroll
        for (int k = 0; k < K2_IT; ++k) {
            float th = l[((size_t)n * NCH + c) * HW + t + k * K2_T];
#pragma unroll
            for (int r = 0; r < K2_R; ++r) s[k][r] += tqc[r] * th;
        }
    }

    float pmax[K2_R];
#pragma unroll
    for (int r = 0; r < K2_R; ++r) pmax[r] = -1e30f;
#pragma unroll
    for (int k = 0; k < K2_IT; ++k)
#pragma unroll
        for (int r = 0; r < K2_R; ++r) pmax[r] = fmaxf(pmax[r], s[k][r]);

    const int lane = t & 63, wid = t >> 6;
#pragma unroll
    for (int r = 0; r < K2_R; ++r) {
        float v = pmax[r];
        for (int off = 32; off > 0; off >>= 1) v = fmaxf(v, __shfl_xor(v, off, 64));
        if (lane == 0) red[wid][r] = v;
    }
    __syncthreads();
    float m[K2_R];
#pragma unroll
    for (int r = 0; r < K2_R; ++r) {
        float v = red[0][r];
#pragma unroll
        for (int wv = 1; wv < 7; ++wv) v = fmaxf(v, red[wv][r]);
        m[r] = v;
    }
    __syncthreads();

    float ps[K2_R];
#pragma unroll
    for (int r = 0; r < K2_R; ++r) ps[r] = 0.f;
#pragma unroll
    for (int k = 0; k < K2_IT; ++k)
#pragma unroll
        for (int r = 0; r < K2_R; ++r) ps[r] += __expf(s[k][r] - m[r]);

#pragma unroll
    for (int r = 0; r < K2_R; ++r) {
        float v = ps[r];
        for (int off = 32; off > 0; off >>= 1) v += __shfl_xor(v, off, 64);
        if (lane == 0) red[wid][r] = v;
    }
    __syncthreads();
    if (t == 0) {
#pragma unroll
        for (int r = 0; r < K2_R; ++r) {
            float v = 0.f;
#pragma unroll
            for (int wv = 0; wv < 7; ++wv) v += red[wv][r];
            mrow[(size_t)n * HW + q0 + r] = m[r];
            zrow[(size_t)n * HW + q0 + r] = 1.f / v;
        }
    }
}

// ---- K3f: fused S-recompute + exp(R) weights + accumulation over a q-slice -----
// block: 64 p columns, QPB q's. 256 thr: (p_l = t&63, grp = t>>6 owns i = grp*16..+15)
__global__ __launch_bounds__(256) void k3f_fused(
    const float* __restrict__ l, const float* __restrict__ Gt,
    const float* __restrict__ mrow, const float* __restrict__ zrow,
    float* __restrict__ Part, float* __restrict__ Zpart)
{
    __shared__ float thq[QT][36];   // [q][c], pad->36 keeps rows 16B-aligned
    __shared__ float Gl[QT][NCH];   // [q][i]
    __shared__ float El[QT][NCH];   // E[q][p_l]
    __shared__ float msh[QT];
    __shared__ float zsh[QT];

    const int t   = threadIdx.x;
    const int p_l = t & 63;
    const int grp = t >> 6;          // 0..3
    const int n   = blockIdx.z;
    const int qsp = blockIdx.y;
    const int p   = blockIdx.x * 64 + p_l;
    const int qbase0 = qsp * QPB;

    float thp[CRED];
#pragma unroll
    for (int c = 0; c < CRED; ++c)
        thp[c] = l[((size_t)n * NCH + c) * HW + p];

    float acc[16];
#pragma unroll
    for (int j = 0; j < 16; ++j) acc[j] = 0.f;
    float zt = 0.f;

    for (int tile = 0; tile < NT; ++tile) {
        const int qb = qbase0 + tile * QT;
        __syncthreads();   // previous tile's reads done
        // stage theta_q tile [qq][c]
#pragma unroll
        for (int rep = 0; rep < 8; ++rep) {
            int e = rep * 256 + t;           // 0..2047
            int c = e >> 6, qq = e & 63;
            thq[qq][c] = l[((size_t)n * NCH + c) * HW + qb + qq];
        }
        // stage G tile [qq][i] (vectorized, coalesced)
#pragma unroll
        for (int rep = 0; rep < 4; ++rep) {
            int e  = rep * 1024 + t * 4;
            int qq = e >> 6, i = e & 63;
            *(float4*)&Gl[qq][i] =
                *(const float4*)&Gt[((size_t)n * HW + qb + qq) * NCH + i];
        }
        if (t < QT)            msh[t]      = mrow[(size_t)n * HW + qb + t];
        else if (t < 2 * QT)   zsh[t - QT] = zrow[(size_t)n * HW + qb + (t - QT)];
        __syncthreads();

        // S + E phase: thread computes q = grp*16 + qq for its p
        float ev[16];
#pragma unroll
        for (int qq = 0; qq < 16; ++qq) {
            const int qr = grp * 16 + qq;
            const float4* tr = (const float4*)&thq[qr][0];
            float s = 0.f;
#pragma unroll
            for (int c4 = 0; c4 < 8; ++c4) {
                float4 v = tr[c4];
                s += v.x * thp[c4 * 4 + 0] + v.y * thp[c4 * 4 + 1]
                   + v.z * thp[c4 * 4 + 2] + v.w * thp[c4 * 4 + 3];
            }
            float r = __expf(s - msh[qr]) * zsh[qr];   // R in (0,1]
            ev[qq] = __expf(r);
        }
#pragma unroll
        for (int qq = 0; qq < 16; ++qq)
            El[grp * 16 + qq][p_l] = ev[qq];
        __syncthreads();

        // accumulation phase: acc[i] += E[qq][p] * G[qq][i]
        const float4* GR = (const float4*)&Gl[0][0];
#pragma unroll 8
        for (int qq = 0; qq < QT; ++qq) {
            float e = El[qq][p_l];
            if (grp == 0) zt += e;
#pragma unroll
            for (int j4 = 0; j4 < 4; ++j4) {
                float4 g = GR[qq * 16 + grp * 4 + j4];
                acc[j4 * 4 + 0] += e * g.x;
                acc[j4 * 4 + 1] += e * g.y;
                acc[j4 * 4 + 2] += e * g.z;
                acc[j4 * 4 + 3] += e * g.w;
            }
        }
    }

    float* Pn = Part + (size_t)(n * QS2 + qsp) * NCH * HW;
#pragma unroll
    for (int j = 0; j < 16; ++j)
        Pn[(size_t)(grp * 16 + j) * HW + p] = acc[j];
    if (grp == 0) Zpart[(size_t)(n * QS2 + qsp) * HW + p] = zt;
}

// ---- K3r: reduce q-slices, divide by Z -> OutPre[n][i][p] ----------------------
__global__ __launch_bounds__(256) void k3r_reduce(
    const float* __restrict__ Part, const float* __restrict__ Zpart,
    float* __restrict__ OutPre)
{
    const int t  = threadIdx.x;
    const int p  = blockIdx.x * 256 + t;
    const int i0 = blockIdx.y * 8;
    const int n  = blockIdx.z;
    if (p >= HW) return;

    float z = 0.f;
#pragma unroll
    for (int qs = 0; qs < QS2; ++qs)
        z += Zpart[(size_t)(n * QS2 + qs) * HW + p];
    const float zi = 1.f / z;

    float* On = OutPre + (size_t)n * NCH * HW;
#pragma unroll
    for (int j = 0; j < 8; ++j) {
        int i = i0 + j;
        float sa = 0.f;
#pragma unroll
        for (int qs = 0; qs < QS2; ++qs)
            sa += Part[((size_t)(n * QS2 + qs) * NCH + i) * HW + p];
        On[(size_t)i * HW + p] = sa * zi;
    }
}

// ---- K4: depthwise 3x3 (pad 1) + BN2 + residual -> fp32 out --------------------
__global__ __launch_bounds__(256) void k4_dwconv(
    const float* __restrict__ OutPre, const float* __restrict__ l,
    const float* __restrict__ wdw,
    const float* __restrict__ gamma, const float* __restrict__ beta,
    const float* __restrict__ mean, const float* __restrict__ var,
    float* __restrict__ out)
{
    const size_t e = (size_t)blockIdx.x * 256 + threadIdx.x;
    if (e >= (size_t)NB * NCH * HW) return;
    const int p = (int)(e % HW);
    const int i = (int)((e / HW) % NCH);
    const int y = p / 56, x = p % 56;
    const float* src = OutPre + (e - p);

    float acc = 0.f;
#pragma unroll
    for (int dy = -1; dy <= 1; ++dy) {
        int yy = y + dy;
        if (yy < 0 || yy >= 56) continue;
#pragma unroll
        for (int dx = -1; dx <= 1; ++dx) {
            int xx = x + dx;
            if (xx < 0 || xx >= 56) continue;
            acc += wdw[i * 9 + (dy + 1) * 3 + (dx + 1)] * src[yy * 56 + xx];
        }
    }
    const float sc = rsqrtf(var[i] + EPSV) * gamma[i];
    float yv = (acc - mean[i]) * sc + beta[i];
    yv += l[e];
    out[e] = yv;
}

// -------------------------------------------------------------------------------
extern "C" void kernel_launch(void* const* d_in, const int* in_sizes, int n_in,
                              void* d_out, int out_size, void* d_ws, size_t ws_size,
                              hipStream_t stream)
{
    const float* l      = (const float*)d_in[0];
    const float* w_in   = (const float*)d_in[1];
    const float* gamma1 = (const float*)d_in[2];
    const float* beta1  = (const float*)d_in[3];
    const float* mean1  = (const float*)d_in[4];
    const float* var1   = (const float*)d_in[5];
    const float* w_dw   = (const float*)d_in[6];
    const float* gamma2 = (const float*)d_in[7];
    const float* beta2  = (const float*)d_in[8];
    const float* mean2  = (const float*)d_in[9];
    const float* var2   = (const float*)d_in[10];
    float* out = (float*)d_out;

    char* ws = (char*)d_ws;
    const size_t szGt    = (size_t)NB * HW * NCH * 4;          // 6.4 MB
    const size_t szOut   = szGt;                               // 6.4 MB
    const size_t szStat  = (size_t)NB * HW * 4;                // 100 KB each
    const size_t szZp    = (size_t)NB * QS2 * HW * 4;          // 0.7 MB
    const size_t szPart  = (size_t)NB * QS2 * NCH * HW * 4;    // 45 MB

    float* Gt     = (float*)ws;
    float* OutPre = (float*)(ws + szGt);
    float* mrow   = (float*)(ws + szGt + szOut);
    float* zrow   = (float*)(ws + szGt + szOut + szStat);
    float* Zp     = (float*)(ws + szGt + szOut + 2 * szStat);
    float* Part   = (float*)(ws + szGt + szOut + 2 * szStat + szZp);
    (void)szPart; (void)ws_size;

    k1_conv1x1<<<dim3(HW / 64, NB), 256, 0, stream>>>(
        l, w_in, gamma1, beta1, mean1, var1, Gt);

    k2s_stats<<<dim3(HW / K2_R, NB), K2_T, 0, stream>>>(l, mrow, zrow);

    k3f_fused<<<dim3(HW / 64, QS2, NB), 256, 0, stream>>>(
        l, Gt, mrow, zrow, Part, Zp);

    k3r_reduce<<<dim3((HW + 255) / 256, NCH / 8, NB), 256, 0, stream>>>(
        Part, Zp, OutPre);

    k4_dwconv<<<dim3((NB * NCH * HW + 255) / 256), 256, 0, stream>>>(
        OutPre, l, w_dw, gamma2, beta2, mean2, var2, out);
}

// Round 4
// 124.155 us; speedup vs baseline: 9.6007x; 3.5291x over previous
//
#include <hip/hip_runtime.h>

#define HW   3136
#define NCH  64
#define CRED 32
#define NB   8
#define EPSV 1e-5f
#define QS2  7

typedef __attribute__((ext_vector_type(8))) short short8;
typedef __attribute__((ext_vector_type(4))) float f32x4;

#define MFMA_B16 __builtin_amdgcn_mfma_f32_16x16x32_bf16

__device__ __forceinline__ unsigned short f2b(float x) {
    union { float f; unsigned u; } v; v.f = x;
    unsigned r = v.u + 0x7fff + ((v.u >> 16) & 1);
    return (unsigned short)(r >> 16);
}
__device__ __forceinline__ unsigned packb(float a, float b) {
    return (unsigned)f2b(a) | ((unsigned)f2b(b) << 16);
}

// ---------------- K1: conv1x1 + BN1 + ReLU6 -> Gt[n][p][i] (fp32) ---------------
__global__ __launch_bounds__(256) void k1_conv1x1(
    const float* __restrict__ l, const float* __restrict__ w,
    const float* __restrict__ gamma, const float* __restrict__ beta,
    const float* __restrict__ mean, const float* __restrict__ var,
    float* __restrict__ Gt)
{
    __shared__ float Wt[NCH][NCH];
    __shared__ float Lt[NCH][64];
    const int t  = threadIdx.x;
    const int n  = blockIdx.y;
    const int p0 = blockIdx.x * 64;

    for (int idx = t; idx < NCH * 64; idx += 256) {
        int c = idx >> 6, i = idx & 63;
        Wt[c][i] = w[i * NCH + c];
        Lt[c][i] = l[((size_t)n * NCH + c) * HW + p0 + i];
    }
    __syncthreads();

    const int i   = t & 63;
    const int pj0 = t >> 6;
    const float mu = mean[i];
    const float sc = rsqrtf(var[i] + EPSV) * gamma[i];
    const float bi = beta[i];

    float acc[16];
#pragma unroll
    for (int k = 0; k < 16; ++k) acc[k] = 0.f;
#pragma unroll
    for (int c = 0; c < NCH; ++c) {
        float wci = Wt[c][i];
#pragma unroll
        for (int k = 0; k < 16; ++k) acc[k] += wci * Lt[c][pj0 + 4 * k];
    }
#pragma unroll
    for (int k = 0; k < 16; ++k) {
        float y = (acc[k] - mu) * sc + bi;
        y = fminf(fmaxf(y, 0.f), 6.f);
        Gt[((size_t)n * HW + p0 + pj0 + 4 * k) * NCH + i] = y;
    }
}

// ------- K2s (MFMA): zpart[psp][n][q] = sum_{p in split} exp(S[q,p]) -----------
__global__ __launch_bounds__(256) void k2s_stats(
    const float* __restrict__ l, float* __restrict__ zpart)
{
    __shared__ unsigned short thq[64][40];
    __shared__ unsigned short thp[64][40];
    const int t = threadIdx.x, w = t >> 6, lane = t & 63;
    const int n = blockIdx.z, psp = blockIdx.y;
    const int q0 = blockIdx.x * 64;

    // stage theta_q tile [qq][c] bf16 (rows padded to 40)
#pragma unroll
    for (int rep = 0; rep < 4; ++rep) {
        int qq = t & 63, c0 = 2 * (t >> 6) + rep * 8;
        float a = l[((size_t)n * NCH + c0) * HW + q0 + qq];
        float b = l[((size_t)n * NCH + c0 + 1) * HW + q0 + qq];
        *(unsigned*)&thq[qq][c0] = packb(a, b);
    }
    __syncthreads();

    // wave w's A-frag: rows q = w*16 + (lane&15), K-half lane>>4
    short8 afrag = *(short8*)&thq[w * 16 + (lane & 15)][(lane >> 4) * 8];

    float z[4] = {0.f, 0.f, 0.f, 0.f};

    for (int pt = 0; pt < 7; ++pt) {
        const int p0 = psp * 448 + pt * 64;
        __syncthreads();
#pragma unroll
        for (int rep = 0; rep < 4; ++rep) {
            int pp = t & 63, c0 = 2 * (t >> 6) + rep * 8;
            float a = l[((size_t)n * NCH + c0) * HW + p0 + pp];
            float b = l[((size_t)n * NCH + c0 + 1) * HW + p0 + pp];
            *(unsigned*)&thp[pp][c0] = packb(a, b);
        }
        __syncthreads();
#pragma unroll
        for (int ss = 0; ss < 4; ++ss) {
            short8 bfrag = *(short8*)&thp[ss * 16 + (lane & 15)][(lane >> 4) * 8];
            f32x4 zero = {0.f, 0.f, 0.f, 0.f};
            f32x4 d = MFMA_B16(afrag, bfrag, zero, 0, 0, 0);
#pragma unroll
            for (int r = 0; r < 4; ++r) z[r] += __expf(d[r]);
        }
    }

    // reduce across the 16 lanes (lane&15) holding one row's columns
#pragma unroll
    for (int r = 0; r < 4; ++r) {
        float v = z[r];
        v += __shfl_xor(v, 1, 64);
        v += __shfl_xor(v, 2, 64);
        v += __shfl_xor(v, 4, 64);
        v += __shfl_xor(v, 8, 64);
        z[r] = v;
    }
    if ((lane & 15) == 0) {
        int q = q0 + w * 16 + (lane >> 4) * 4;
        f32x4 st = {z[0], z[1], z[2], z[3]};
        *(f32x4*)&zpart[((size_t)psp * NB + n) * HW + q] = st;
    }
}

// ------- K2c: crow[n][q] = log(sum_psp zpart) ----------------------------------
__global__ __launch_bounds__(256) void k2c_combine(
    const float* __restrict__ zpart, float* __restrict__ crow)
{
    const int idx = blockIdx.x * 256 + threadIdx.x;
    if (idx >= NB * HW) return;
    float s = 0.f;
#pragma unroll
    for (int ps = 0; ps < QS2; ++ps) s += zpart[(size_t)ps * NB * HW + idx];
    crow[idx] = __logf(s);
}

// ---- K3f (MFMA): S recompute + E=exp(exp(S-c)) + PV over q-slice --------------
__global__ __launch_bounds__(256) void k3f_fused(
    const float* __restrict__ l, const float* __restrict__ Gt,
    const float* __restrict__ crow,
    float* __restrict__ Part, float* __restrict__ Zpart)
{
    __shared__ unsigned short thp[64][40];   // theta_p  [p][c]
    __shared__ unsigned short thq[64][40];   // theta_q  [q][c]
    __shared__ unsigned short Glt[64][72];   // G^T      [i][q]
    __shared__ unsigned short El[64][72];    // E        [p][q]
    __shared__ float csh[64];

    const int t = threadIdx.x, w = t >> 6, lane = t & 63;
    const int n = blockIdx.z, qsp = blockIdx.y;
    const int pblk = blockIdx.x * 64;
    const int pw = w * 16;

    // stage theta_p (block-invariant)
#pragma unroll
    for (int rep = 0; rep < 4; ++rep) {
        int pp = t & 63, c0 = 2 * (t >> 6) + rep * 8;
        float a = l[((size_t)n * NCH + c0) * HW + pblk + pp];
        float b = l[((size_t)n * NCH + c0 + 1) * HW + pblk + pp];
        *(unsigned*)&thp[pp][c0] = packb(a, b);
    }
    __syncthreads();
    short8 bp = *(short8*)&thp[pw + (lane & 15)][(lane >> 4) * 8];

    f32x4 acc[4];
#pragma unroll
    for (int it = 0; it < 4; ++it) acc[it] = (f32x4){0.f, 0.f, 0.f, 0.f};
    float zl = 0.f;

    for (int tile = 0; tile < 7; ++tile) {
        const int qb = qsp * 448 + tile * 64;
        __syncthreads();
        // stage theta_q
#pragma unroll
        for (int rep = 0; rep < 4; ++rep) {
            int qq = t & 63, c0 = 2 * (t >> 6) + rep * 8;
            float a = l[((size_t)n * NCH + c0) * HW + qb + qq];
            float b = l[((size_t)n * NCH + c0 + 1) * HW + qb + qq];
            *(unsigned*)&thq[qq][c0] = packb(a, b);
        }
        // stage G transposed: Glt[i][q]
#pragma unroll
        for (int rep = 0; rep < 2; ++rep) {
            int i0 = (t & 15) * 4, qq0 = (t >> 4) * 2 + rep * 32;
            const float4 g0 = *(const float4*)&Gt[((size_t)n * HW + qb + qq0) * NCH + i0];
            const float4 g1 = *(const float4*)&Gt[((size_t)n * HW + qb + qq0 + 1) * NCH + i0];
            *(unsigned*)&Glt[i0 + 0][qq0] = packb(g0.x, g1.x);
            *(unsigned*)&Glt[i0 + 1][qq0] = packb(g0.y, g1.y);
            *(unsigned*)&Glt[i0 + 2][qq0] = packb(g0.z, g1.z);
            *(unsigned*)&Glt[i0 + 3][qq0] = packb(g0.w, g1.w);
        }
        if (t < 64) csh[t] = crow[(size_t)n * HW + qb + t];
        __syncthreads();

        // S phase: 4 q-subtiles of 16; write E rows into El[p][q]
#pragma unroll
        for (int s = 0; s < 4; ++s) {
            short8 aq = *(short8*)&thq[s * 16 + (lane & 15)][(lane >> 4) * 8];
            f32x4 zero = {0.f, 0.f, 0.f, 0.f};
            f32x4 d = MFMA_B16(aq, bp, zero, 0, 0, 0);
            f32x4 cv = *(f32x4*)&csh[s * 16 + (lane >> 4) * 4];
            unsigned pk[2];
            float e0, e1;
            e0 = __expf(__expf(d[0] - cv[0]));
            e1 = __expf(__expf(d[1] - cv[1]));
            zl += e0 + e1;
            pk[0] = packb(e0, e1);
            e0 = __expf(__expf(d[2] - cv[2]));
            e1 = __expf(__expf(d[3] - cv[3]));
            zl += e0 + e1;
            pk[1] = packb(e0, e1);
            unsigned* dst = (unsigned*)&El[pw + (lane & 15)][s * 16 + (lane >> 4) * 4];
            dst[0] = pk[0];
            dst[1] = pk[1];
        }

        // PV phase: acc[it] (D[p][i]) += El[p][q-k] * Glt[i][q-k]
#pragma unroll
        for (int ks = 0; ks < 2; ++ks) {
            short8 ae = *(short8*)&El[pw + (lane & 15)][ks * 32 + (lane >> 4) * 8];
#pragma unroll
            for (int it = 0; it < 4; ++it) {
                short8 bg = *(short8*)&Glt[it * 16 + (lane & 15)][ks * 32 + (lane >> 4) * 8];
                acc[it] = MFMA_B16(ae, bg, acc[it], 0, 0, 0);
            }
        }
    }

    // write Part[n,qsp][i][p]: lane holds D[p = pw+(lane>>4)*4+reg][i = it*16+(lane&15)]
    float* Pn = Part + ((size_t)n * QS2 + qsp) * (size_t)NCH * HW;
#pragma unroll
    for (int it = 0; it < 4; ++it) {
        *(f32x4*)&Pn[(size_t)(it * 16 + (lane & 15)) * HW + pblk + pw + (lane >> 4) * 4] = acc[it];
    }
    // Z: sum zl across the 4 lane>>4 groups (each covered distinct q rows)
    zl += __shfl_xor(zl, 16, 64);
    zl += __shfl_xor(zl, 32, 64);
    if (lane < 16)
        Zpart[((size_t)n * QS2 + qsp) * HW + pblk + pw + lane] = zl;
}

// ---- K3r: reduce q-slices, divide by Z -> OutPre[n][i][p] ----------------------
__global__ __launch_bounds__(256) void k3r_reduce(
    const float* __restrict__ Part, const float* __restrict__ Zpart,
    float* __restrict__ OutPre)
{
    const int t  = threadIdx.x;
    const int p  = blockIdx.x * 256 + t;
    const int i0 = blockIdx.y * 8;
    const int n  = blockIdx.z;
    if (p >= HW) return;

    float z = 0.f;
#pragma unroll
    for (int qs = 0; qs < QS2; ++qs)
        z += Zpart[((size_t)n * QS2 + qs) * HW + p];
    const float zi = 1.f / z;

    float* On = OutPre + (size_t)n * NCH * HW;
#pragma unroll
    for (int j = 0; j < 8; ++j) {
        int i = i0 + j;
        float sa = 0.f;
#pragma unroll
        for (int qs = 0; qs < QS2; ++qs)
            sa += Part[(((size_t)n * QS2 + qs) * NCH + i) * HW + p];
        On[(size_t)i * HW + p] = sa * zi;
    }
}

// ---- K4: depthwise 3x3 (pad 1) + BN2 + residual -> fp32 out --------------------
__global__ __launch_bounds__(256) void k4_dwconv(
    const float* __restrict__ OutPre, const float* __restrict__ l,
    const float* __restrict__ wdw,
    const float* __restrict__ gamma, const float* __restrict__ beta,
    const float* __restrict__ mean, const float* __restrict__ var,
    float* __restrict__ out)
{
    const size_t e = (size_t)blockIdx.x * 256 + threadIdx.x;
    if (e >= (size_t)NB * NCH * HW) return;
    const int p = (int)(e % HW);
    const int i = (int)((e / HW) % NCH);
    const int y = p / 56, x = p % 56;
    const float* src = OutPre + (e - p);

    float acc = 0.f;
#pragma unroll
    for (int dy = -1; dy <= 1; ++dy) {
        int yy = y + dy;
        if (yy < 0 || yy >= 56) continue;
#pragma unroll
        for (int dx = -1; dx <= 1; ++dx) {
            int xx = x + dx;
            if (xx < 0 || xx >= 56) continue;
            acc += wdw[i * 9 + (dy + 1) * 3 + (dx + 1)] * src[yy * 56 + xx];
        }
    }
    const float sc = rsqrtf(var[i] + EPSV) * gamma[i];
    float yv = (acc - mean[i]) * sc + beta[i];
    yv += l[e];
    out[e] = yv;
}

// -------------------------------------------------------------------------------
extern "C" void kernel_launch(void* const* d_in, const int* in_sizes, int n_in,
                              void* d_out, int out_size, void* d_ws, size_t ws_size,
                              hipStream_t stream)
{
    const float* l      = (const float*)d_in[0];
    const float* w_in   = (const float*)d_in[1];
    const float* gamma1 = (const float*)d_in[2];
    const float* beta1  = (const float*)d_in[3];
    const float* mean1  = (const float*)d_in[4];
    const float* var1   = (const float*)d_in[5];
    const float* w_dw   = (const float*)d_in[6];
    const float* gamma2 = (const float*)d_in[7];
    const float* beta2  = (const float*)d_in[8];
    const float* mean2  = (const float*)d_in[9];
    const float* var2   = (const float*)d_in[10];
    float* out = (float*)d_out;

    char* ws = (char*)d_ws;
    const size_t szGt   = (size_t)NB * HW * NCH * 4;          // 6.4 MB (also OutPre)
    const size_t szCrow = (size_t)NB * HW * 4;                // 100 KB
    const size_t szZpt  = (size_t)QS2 * NB * HW * 4;          // 0.7 MB
    const size_t szZp   = (size_t)NB * QS2 * HW * 4;          // 0.7 MB

    float* Gt     = (float*)ws;                                // aliased: OutPre after k3f
    float* OutPre = Gt;
    float* crow   = (float*)(ws + szGt);
    float* zpart  = (float*)(ws + szGt + szCrow);
    float* Zp     = (float*)(ws + szGt + szCrow + szZpt);
    float* Part   = (float*)(ws + szGt + szCrow + szZpt + szZp);
    (void)ws_size;

    k1_conv1x1<<<dim3(HW / 64, NB), 256, 0, stream>>>(
        l, w_in, gamma1, beta1, mean1, var1, Gt);

    k2s_stats<<<dim3(HW / 64, QS2, NB), 256, 0, stream>>>(l, zpart);

    k2c_combine<<<dim3((NB * HW) / 256), 256, 0, stream>>>(zpart, crow);

    k3f_fused<<<dim3(HW / 64, QS2, NB), 256, 0, stream>>>(l, Gt, crow, Part, Zp);

    k3r_reduce<<<dim3((HW + 255) / 256, NCH / 8, NB), 256, 0, stream>>>(
        Part, Zp, OutPre);

    k4_dwconv<<<dim3((NB * NCH * HW + 255) / 256), 256, 0, stream>>>(
        OutPre, l, w_dw, gamma2, beta2, mean2, var2, out);
}

// Round 5
// 110.389 us; speedup vs baseline: 10.7981x; 1.1247x over previous
//
#include <hip/hip_runtime.h>

#define HW   3136
#define NCH  64
#define CRED 32
#define NB   8
#define EPSV 1e-5f
#define QS2  7

typedef __attribute__((ext_vector_type(8))) short short8;
typedef __attribute__((ext_vector_type(4))) short short4v;
typedef __attribute__((ext_vector_type(4))) float f32x4;
typedef __attribute__((ext_vector_type(2))) float f32x2;
typedef _Float16 half_t;
typedef __attribute__((ext_vector_type(2))) _Float16 half2v;
typedef __attribute__((ext_vector_type(4))) _Float16 half4v;

#define MFMA_B16 __builtin_amdgcn_mfma_f32_16x16x32_bf16

__device__ __forceinline__ unsigned short f2b(float x) {
    union { float f; unsigned u; } v; v.f = x;
    unsigned r = v.u + 0x7fff + ((v.u >> 16) & 1);
    return (unsigned short)(r >> 16);
}

// ---- K1: conv1x1 + BN1 + ReLU6 -> Gbt[n][i][p] bf16; also theta_bf[n][p][c] ----
__global__ __launch_bounds__(256) void k1_conv1x1(
    const float* __restrict__ l, const float* __restrict__ w,
    const float* __restrict__ gamma, const float* __restrict__ beta,
    const float* __restrict__ mean, const float* __restrict__ var,
    unsigned short* __restrict__ theta_bf, unsigned short* __restrict__ Gbt)
{
    __shared__ float Wt[NCH][65];   // Wt[c][i]; reused as G-transpose [i][p]
    __shared__ float Lt[NCH][65];   // Lt[c][j]
    const int t  = threadIdx.x;
    const int n  = blockIdx.y;
    const int p0 = blockIdx.x * 64;

    for (int idx = t; idx < NCH * 64; idx += 256) {
        int c = idx >> 6, j = idx & 63;
        Wt[c][j] = w[j * NCH + c];
        Lt[c][j] = l[((size_t)n * NCH + c) * HW + p0 + j];
    }
    __syncthreads();

    // emit theta_bf[n][p0+p][c0..c0+7]
    {
        const int p = t >> 2, c0 = (t & 3) * 8;
        unsigned short pk[8];
#pragma unroll
        for (int j = 0; j < 8; ++j) pk[j] = f2b(Lt[c0 + j][p]);
        *(short8*)&theta_bf[((size_t)n * HW + p0 + p) * CRED + c0] = *(short8*)pk;
    }

    const int i   = t & 63;
    const int pj0 = t >> 6;
    const float mu = mean[i];
    const float sc = rsqrtf(var[i] + EPSV) * gamma[i];
    const float bi = beta[i];

    float acc[16];
#pragma unroll
    for (int k = 0; k < 16; ++k) acc[k] = 0.f;
#pragma unroll
    for (int c = 0; c < NCH; ++c) {
        float wci = Wt[c][i];
#pragma unroll
        for (int k = 0; k < 16; ++k) acc[k] += wci * Lt[c][pj0 + 4 * k];
    }
    __syncthreads();   // all reads of Wt done before reuse

#pragma unroll
    for (int k = 0; k < 16; ++k) {
        float y = (acc[k] - mu) * sc + bi;
        y = fminf(fmaxf(y, 0.f), 6.f);
        Wt[i][pj0 + 4 * k] = y;        // transpose buffer [i][p]
    }
    __syncthreads();

    {
        const int ir = t >> 2, pc = (t & 3) * 16;
        unsigned short pk[16];
#pragma unroll
        for (int j = 0; j < 16; ++j) pk[j] = f2b(Wt[ir][pc + j]);
        unsigned short* dst = &Gbt[((size_t)n * NCH + ir) * HW + p0 + pc];
        *(short8*)&dst[0] = *(short8*)&pk[0];
        *(short8*)&dst[8] = *(short8*)&pk[8];
    }
}

// ---- K2s (MFMA, no LDS): zpart[psp][n][q] = sum_{p in split} exp(S[q,p]) -------
__global__ __launch_bounds__(256) void k2s_stats(
    const unsigned short* __restrict__ theta_bf, float* __restrict__ zpart)
{
    const int t = threadIdx.x, w = t >> 6, lane = t & 63;
    const int lo = lane & 15, hi = lane >> 4;
    const int n = blockIdx.z, psp = blockIdx.y;
    const int q0 = blockIdx.x * 64;

    const short8 afrag =
        *(const short8*)&theta_bf[((size_t)n * HW + q0 + w * 16 + lo) * CRED + hi * 8];

    float z[4] = {0.f, 0.f, 0.f, 0.f};
    for (int pt = 0; pt < 7; ++pt) {
        const int p0 = psp * 448 + pt * 64;
#pragma unroll
        for (int ss = 0; ss < 4; ++ss) {
            const short8 bfrag =
                *(const short8*)&theta_bf[((size_t)n * HW + p0 + ss * 16 + lo) * CRED + hi * 8];
            f32x4 zero = {0.f, 0.f, 0.f, 0.f};
            f32x4 d = MFMA_B16(afrag, bfrag, zero, 0, 0, 0);
#pragma unroll
            for (int r = 0; r < 4; ++r) z[r] += __expf(d[r]);
        }
    }

#pragma unroll
    for (int r = 0; r < 4; ++r) {
        float v = z[r];
        v += __shfl_xor(v, 1, 64);
        v += __shfl_xor(v, 2, 64);
        v += __shfl_xor(v, 4, 64);
        v += __shfl_xor(v, 8, 64);
        z[r] = v;
    }
    if (lo == 0) {
        f32x4 st = {z[0], z[1], z[2], z[3]};
        *(f32x4*)&zpart[((size_t)psp * NB + n) * HW + q0 + w * 16 + hi * 4] = st;
    }
}

// ---- K2c: crow[n][q] = log(sum_psp zpart) --------------------------------------
__global__ __launch_bounds__(256) void k2c_combine(
    const float* __restrict__ zpart, float* __restrict__ crow)
{
    const int idx = blockIdx.x * 256 + threadIdx.x;
    float s = 0.f;
#pragma unroll
    for (int ps = 0; ps < QS2; ++ps) s += zpart[(size_t)ps * NB * HW + idx];
    crow[idx] = __logf(s);
}

// ---- K3f (MFMA): S recompute + E=exp(exp(S-c)) + PV over q-slice ---------------
__global__ __launch_bounds__(256) void k3f_fused(
    const unsigned short* __restrict__ theta_bf,
    const unsigned short* __restrict__ Gbt,
    const float* __restrict__ crow,
    half_t* __restrict__ Part, float* __restrict__ Zpart)
{
    __shared__ unsigned short Glt[64][72];   // G^T [i][q]
    __shared__ unsigned short El[64][72];    // E   [p][q]

    const int t = threadIdx.x, w = t >> 6, lane = t & 63;
    const int lo = lane & 15, hi = lane >> 4;
    const int n = blockIdx.z, qsp = blockIdx.y;
    const int pblk = blockIdx.x * 64;
    const int pw = w * 16;

    // block-invariant theta_p fragment, direct from global
    const short8 bp =
        *(const short8*)&theta_bf[((size_t)n * HW + pblk + pw + lo) * CRED + hi * 8];

    f32x4 acc[4];
#pragma unroll
    for (int it = 0; it < 4; ++it) acc[it] = (f32x4){0.f, 0.f, 0.f, 0.f};
    float zl = 0.f;

    for (int tile = 0; tile < 7; ++tile) {
        const int qb = qsp * 448 + tile * 64;
        __syncthreads();
        // stage G^T tile: pure bf16 row copy
        {
            const int ir = t >> 2, qoff = (t & 3) * 16;
            const unsigned short* src = &Gbt[((size_t)n * NCH + ir) * HW + qb + qoff];
            *(short8*)&Glt[ir][qoff]     = *(const short8*)&src[0];
            *(short8*)&Glt[ir][qoff + 8] = *(const short8*)&src[8];
        }
        __syncthreads();

        // S phase: 4 q-subtiles; E rows -> El[p][q]
#pragma unroll
        for (int s = 0; s < 4; ++s) {
            const short8 aq =
                *(const short8*)&theta_bf[((size_t)n * HW + qb + s * 16 + lo) * CRED + hi * 8];
            f32x4 zero = {0.f, 0.f, 0.f, 0.f};
            f32x4 d = MFMA_B16(aq, bp, zero, 0, 0, 0);
            const f32x4 cv = *(const f32x4*)&crow[(size_t)n * HW + qb + s * 16 + hi * 4];
            short4v ev;
            float e0 = __expf(__expf(d[0] - cv[0]));
            float e1 = __expf(__expf(d[1] - cv[1]));
            float e2 = __expf(__expf(d[2] - cv[2]));
            float e3 = __expf(__expf(d[3] - cv[3]));
            zl += (e0 + e1) + (e2 + e3);
            ev[0] = (short)f2b(e0); ev[1] = (short)f2b(e1);
            ev[2] = (short)f2b(e2); ev[3] = (short)f2b(e3);
            *(short4v*)&El[pw + lo][s * 16 + hi * 4] = ev;
        }

        // PV phase: acc[it] (D[p][i]) += El[p][q] * Glt[i][q]
#pragma unroll
        for (int ks = 0; ks < 2; ++ks) {
            const short8 ae = *(const short8*)&El[pw + lo][ks * 32 + hi * 8];
#pragma unroll
            for (int it = 0; it < 4; ++it) {
                const short8 bg = *(const short8*)&Glt[it * 16 + lo][ks * 32 + hi * 8];
                acc[it] = MFMA_B16(ae, bg, acc[it], 0, 0, 0);
            }
        }
    }

    // Part[n,qsp][i][p] fp16
    half_t* Pn = Part + ((size_t)n * QS2 + qsp) * (size_t)NCH * HW;
#pragma unroll
    for (int it = 0; it < 4; ++it) {
        half4v h;
        h[0] = (half_t)acc[it][0]; h[1] = (half_t)acc[it][1];
        h[2] = (half_t)acc[it][2]; h[3] = (half_t)acc[it][3];
        *(half4v*)&Pn[(size_t)(it * 16 + lo) * HW + pblk + pw + hi * 4] = h;
    }
    zl += __shfl_xor(zl, 16, 64);
    zl += __shfl_xor(zl, 32, 64);
    if (lane < 16)
        Zpart[((size_t)n * QS2 + qsp) * HW + pblk + pw + lane] = zl;
}

// ---- K3r: reduce q-slices (fp16 parts), divide by Z -> OutPre[n][i][p] ---------
__global__ __launch_bounds__(256) void k3r_reduce(
    const half_t* __restrict__ Part, const float* __restrict__ Zpart,
    float* __restrict__ OutPre)
{
    const int t  = threadIdx.x;
    const int p2 = blockIdx.x * 256 + t;       // pair index
    const int i0 = blockIdx.y * 8;
    const int n  = blockIdx.z;
    if (p2 >= HW / 2) return;
    const int p = p2 * 2;

    f32x2 z = {0.f, 0.f};
#pragma unroll
    for (int qs = 0; qs < QS2; ++qs) {
        f32x2 zv = *(const f32x2*)&Zpart[((size_t)n * QS2 + qs) * HW + p];
        z += zv;
    }
    const float zix = 1.f / z[0], ziy = 1.f / z[1];

    float* On = OutPre + (size_t)n * NCH * HW;
#pragma unroll
    for (int j = 0; j < 8; ++j) {
        const int i = i0 + j;
        float sx = 0.f, sy = 0.f;
#pragma unroll
        for (int qs = 0; qs < QS2; ++qs) {
            half2v h = *(const half2v*)&Part[(((size_t)n * QS2 + qs) * NCH + i) * HW + p];
            sx += (float)h[0];
            sy += (float)h[1];
        }
        f32x2 o = {sx * zix, sy * ziy};
        *(f32x2*)&On[(size_t)i * HW + p] = o;
    }
}

// ---- K4: depthwise 3x3 (pad 1) + BN2 + residual -> fp32 out --------------------
__global__ __launch_bounds__(256) void k4_dwconv(
    const float* __restrict__ OutPre, const float* __restrict__ l,
    const float* __restrict__ wdw,
    const float* __restrict__ gamma, const float* __restrict__ beta,
    const float* __restrict__ mean, const float* __restrict__ var,
    float* __restrict__ out)
{
    const size_t e = (size_t)blockIdx.x * 256 + threadIdx.x;
    const int p = (int)(e % HW);
    const int i = (int)((e / HW) % NCH);
    const int y = p / 56, x = p % 56;
    const float* src = OutPre + (e - p);

    float acc = 0.f;
#pragma unroll
    for (int dy = -1; dy <= 1; ++dy) {
        int yy = y + dy;
        if (yy < 0 || yy >= 56) continue;
#pragma unroll
        for (int dx = -1; dx <= 1; ++dx) {
            int xx = x + dx;
            if (xx < 0 || xx >= 56) continue;
            acc += wdw[i * 9 + (dy + 1) * 3 + (dx + 1)] * src[yy * 56 + xx];
        }
    }
    const float sc = rsqrtf(var[i] + EPSV) * gamma[i];
    float yv = (acc - mean[i]) * sc + beta[i];
    yv += l[e];
    out[e] = yv;
}

// -------------------------------------------------------------------------------
extern "C" void kernel_launch(void* const* d_in, const int* in_sizes, int n_in,
                              void* d_out, int out_size, void* d_ws, size_t ws_size,
                              hipStream_t stream)
{
    const float* l      = (const float*)d_in[0];
    const float* w_in   = (const float*)d_in[1];
    const float* gamma1 = (const float*)d_in[2];
    const float* beta1  = (const float*)d_in[3];
    const float* mean1  = (const float*)d_in[4];
    const float* var1   = (const float*)d_in[5];
    const float* w_dw   = (const float*)d_in[6];
    const float* gamma2 = (const float*)d_in[7];
    const float* beta2  = (const float*)d_in[8];
    const float* mean2  = (const float*)d_in[9];
    const float* var2   = (const float*)d_in[10];
    float* out = (float*)d_out;

    char* ws = (char*)d_ws;
    const size_t szTheta = (size_t)NB * HW * CRED * 2;        // 1.6 MB
    const size_t szGbt   = (size_t)NB * NCH * HW * 2;         // 3.2 MB
    const size_t szOut   = (size_t)NB * NCH * HW * 4;         // 6.4 MB
    const size_t szCrow  = (size_t)NB * HW * 4;               // 100 KB
    const size_t szZpt   = (size_t)QS2 * NB * HW * 4;         // 0.7 MB
    const size_t szZp    = (size_t)NB * QS2 * HW * 4;         // 0.7 MB

    unsigned short* theta_bf = (unsigned short*)ws;
    unsigned short* Gbt      = (unsigned short*)(ws + szTheta);
    float* OutPre = (float*)(ws + szTheta + szGbt);
    float* crow   = (float*)(ws + szTheta + szGbt + szOut);
    float* zpart  = (float*)(ws + szTheta + szGbt + szOut + szCrow);
    float* Zp     = (float*)(ws + szTheta + szGbt + szOut + szCrow + szZpt);
    half_t* Part  = (half_t*)(ws + szTheta + szGbt + szOut + szCrow + szZpt + szZp);
    (void)ws_size;

    k1_conv1x1<<<dim3(HW / 64, NB), 256, 0, stream>>>(
        l, w_in, gamma1, beta1, mean1, var1, theta_bf, Gbt);

    k2s_stats<<<dim3(HW / 64, QS2, NB), 256, 0, stream>>>(theta_bf, zpart);

    k2c_combine<<<dim3((NB * HW) / 256), 256, 0, stream>>>(zpart, crow);

    k3f_fused<<<dim3(HW / 64, QS2, NB), 256, 0, stream>>>(
        theta_bf, Gbt, crow, Part, Zp);

    k3r_reduce<<<dim3((HW / 2 + 255) / 256, NCH / 8, NB), 256, 0, stream>>>(
        Part, Zp, OutPre);

    k4_dwconv<<<dim3((NB * NCH * HW) / 256), 256, 0, stream>>>(
        OutPre, l, w_dw, gamma2, beta2, mean2, var2, out);
}

// Round 7
// 105.174 us; speedup vs baseline: 11.3335x; 1.0496x over previous
//
#include <hip/hip_runtime.h>

#define HW   3136
#define NCH  64
#define CRED 32
#define NB   8
#define EPSV 1e-5f
#define QS2  7

// sqrt(log2(e)) — both theta operands scaled => S' = S * log2(e)
#define SQRT_L2E 1.2011224087f
// log2(log2(e))
#define LOG2_L2E 0.5287663729f

typedef __attribute__((ext_vector_type(8))) short short8;
typedef __attribute__((ext_vector_type(4))) float f32x4;
typedef __attribute__((ext_vector_type(2))) float f32x2;
typedef _Float16 half_t;
typedef __attribute__((ext_vector_type(2))) _Float16 half2v;
typedef __attribute__((ext_vector_type(4))) _Float16 half4v;

#define MFMA_B16 __builtin_amdgcn_mfma_f32_16x16x32_bf16

__device__ __forceinline__ unsigned short f2b(float x) {
    union { float f; unsigned u; } v; v.f = x;
    unsigned r = v.u + 0x7fff + ((v.u >> 16) & 1);
    return (unsigned short)(r >> 16);
}

// raw v_exp_f32: 2^x
__device__ __forceinline__ float ex2(float x) {
#if __has_builtin(__builtin_amdgcn_exp2f)
    return __builtin_amdgcn_exp2f(x);
#else
    float r;
    asm volatile("v_exp_f32 %0, %1" : "=v"(r) : "v"(x));
    return r;
#endif
}

// pack two f32 -> bf16x2 in one instruction
__device__ __forceinline__ unsigned cvtpk(float a, float b) {
    unsigned r;
    asm("v_cvt_pk_bf16_f32 %0, %1, %2" : "=v"(r) : "v"(a), "v"(b));
    return r;
}

// ---- K1: conv1x1 + BN1 + ReLU6 -> Gbt[n][i][p] bf16; theta_bf[n][p][c] scaled --
__global__ __launch_bounds__(256) void k1_conv1x1(
    const float* __restrict__ l, const float* __restrict__ w,
    const float* __restrict__ gamma, const float* __restrict__ beta,
    const float* __restrict__ mean, const float* __restrict__ var,
    unsigned short* __restrict__ theta_bf, unsigned short* __restrict__ Gbt)
{
    __shared__ float Wt[NCH][65];   // Wt[c][i]; reused as G-transpose [i][p]
    __shared__ float Lt[NCH][65];   // Lt[c][j]
    const int t  = threadIdx.x;
    const int n  = blockIdx.y;
    const int p0 = blockIdx.x * 64;

    for (int idx = t; idx < NCH * 64; idx += 256) {
        int c = idx >> 6, j = idx & 63;
        Wt[c][j] = w[j * NCH + c];
        Lt[c][j] = l[((size_t)n * NCH + c) * HW + p0 + j];
    }
    __syncthreads();

    // emit theta_bf[n][p0+p][c0..c0+7], pre-scaled by sqrt(log2 e)
    {
        const int p = t >> 2, c0 = (t & 3) * 8;
        unsigned short pk[8];
#pragma unroll
        for (int j = 0; j < 8; ++j) pk[j] = f2b(Lt[c0 + j][p] * SQRT_L2E);
        *(short8*)&theta_bf[((size_t)n * HW + p0 + p) * CRED + c0] = *(short8*)pk;
    }

    const int i   = t & 63;
    const int pj0 = t >> 6;
    const float mu = mean[i];
    const float sc = rsqrtf(var[i] + EPSV) * gamma[i];
    const float bi = beta[i];

    float acc[16];
#pragma unroll
    for (int k = 0; k < 16; ++k) acc[k] = 0.f;
#pragma unroll
    for (int c = 0; c < NCH; ++c) {
        float wci = Wt[c][i];
#pragma unroll
        for (int k = 0; k < 16; ++k) acc[k] += wci * Lt[c][pj0 + 4 * k];
    }
    __syncthreads();   // all reads of Wt done before reuse

#pragma unroll
    for (int k = 0; k < 16; ++k) {
        float y = (acc[k] - mu) * sc + bi;
        y = fminf(fmaxf(y, 0.f), 6.f);
        Wt[i][pj0 + 4 * k] = y;        // transpose buffer [i][p]
    }
    __syncthreads();

    {
        const int ir = t >> 2, pc = (t & 3) * 16;
        unsigned short pk[16];
#pragma unroll
        for (int j = 0; j < 16; ++j) pk[j] = f2b(Wt[ir][pc + j]);
        unsigned short* dst = &Gbt[((size_t)n * NCH + ir) * HW + p0 + pc];
        *(short8*)&dst[0] = *(short8*)&pk[0];
        *(short8*)&dst[8] = *(short8*)&pk[8];
    }
}

// ---- K2s (MFMA, no LDS): zpart[psp][n][q] = sum_{p in split} 2^(S'[q,p]) -------
__global__ __launch_bounds__(256) void k2s_stats(
    const unsigned short* __restrict__ theta_bf, float* __restrict__ zpart)
{
    const int t = threadIdx.x, w = t >> 6, lane = t & 63;
    const int lo = lane & 15, hi = lane >> 4;
    const int n = blockIdx.z, psp = blockIdx.y;
    const int q0 = blockIdx.x * 64;

    const short8 afrag =
        *(const short8*)&theta_bf[((size_t)n * HW + q0 + w * 16 + lo) * CRED + hi * 8];

    float z[4] = {0.f, 0.f, 0.f, 0.f};
    for (int pt = 0; pt < 7; ++pt) {
        const int p0 = psp * 448 + pt * 64;
#pragma unroll
        for (int ss = 0; ss < 4; ++ss) {
            const short8 bfrag =
                *(const short8*)&theta_bf[((size_t)n * HW + p0 + ss * 16 + lo) * CRED + hi * 8];
            f32x4 zero = {0.f, 0.f, 0.f, 0.f};
            f32x4 d = MFMA_B16(afrag, bfrag, zero, 0, 0, 0);
#pragma unroll
            for (int r = 0; r < 4; ++r) z[r] += ex2(d[r]);
        }
    }

#pragma unroll
    for (int r = 0; r < 4; ++r) {
        float v = z[r];
        v += __shfl_xor(v, 1, 64);
        v += __shfl_xor(v, 2, 64);
        v += __shfl_xor(v, 4, 64);
        v += __shfl_xor(v, 8, 64);
        z[r] = v;
    }
    if (lo == 0) {
        f32x4 st = {z[0], z[1], z[2], z[3]};
        *(f32x4*)&zpart[((size_t)psp * NB + n) * HW + q0 + w * 16 + hi * 4] = st;
    }
}

// ---- K2c: crow[n][q] = log2(log2 e) - log2(sum_psp zpart) ----------------------
__global__ __launch_bounds__(256) void k2c_combine(
    const float* __restrict__ zpart, float* __restrict__ crow)
{
    const int idx = blockIdx.x * 256 + threadIdx.x;
    float s = 0.f;
#pragma unroll
    for (int ps = 0; ps < QS2; ++ps) s += zpart[(size_t)ps * NB * HW + idx];
    crow[idx] = LOG2_L2E - __log2f(s);
}

// ---- K3f (MFMA): d = S' + crow (C-operand); E = 2^(2^d); PV over q-slice -------
__global__ __launch_bounds__(256) void k3f_fused(
    const unsigned short* __restrict__ theta_bf,
    const unsigned short* __restrict__ Gbt,
    const float* __restrict__ crow,
    half_t* __restrict__ Part, float* __restrict__ Zpart)
{
    __shared__ unsigned short Glt[64][76];   // G^T [i][q], pad 76 -> 16 distinct banks
    __shared__ unsigned short El[64][76];    // E   [p][q]

    const int t = threadIdx.x, w = t >> 6, lane = t & 63;
    const int lo = lane & 15, hi = lane >> 4;
    const int n = blockIdx.z, qsp = blockIdx.y;
    const int pblk = blockIdx.x * 64;
    const int pw = w * 16;

    // block-invariant theta_p fragment, direct from global
    const short8 bp =
        *(const short8*)&theta_bf[((size_t)n * HW + pblk + pw + lo) * CRED + hi * 8];

    f32x4 acc[4];
#pragma unroll
    for (int it = 0; it < 4; ++it) acc[it] = (f32x4){0.f, 0.f, 0.f, 0.f};
    float zl = 0.f;

    for (int tile = 0; tile < 7; ++tile) {
        const int qb = qsp * 448 + tile * 64;
        __syncthreads();
        // stage G^T tile: pure bf16 row copy
        {
            const int ir = t >> 2, qoff = (t & 3) * 16;
            const unsigned short* src = &Gbt[((size_t)n * NCH + ir) * HW + qb + qoff];
            *(short8*)&Glt[ir][qoff]     = *(const short8*)&src[0];
            *(short8*)&Glt[ir][qoff + 8] = *(const short8*)&src[8];
        }
        __syncthreads();

        // S phase: 4 q-subtiles; E rows -> El[p][q]
#pragma unroll
        for (int s = 0; s < 4; ++s) {
            const short8 aq =
                *(const short8*)&theta_bf[((size_t)n * HW + qb + s * 16 + lo) * CRED + hi * 8];
            const f32x4 cv = *(const f32x4*)&crow[(size_t)n * HW + qb + s * 16 + hi * 4];
            f32x4 d = MFMA_B16(aq, bp, cv, 0, 0, 0);
            float e0 = ex2(ex2(d[0]));
            float e1 = ex2(ex2(d[1]));
            float e2 = ex2(ex2(d[2]));
            float e3 = ex2(ex2(d[3]));
            zl += (e0 + e1) + (e2 + e3);
            unsigned* dst = (unsigned*)&El[pw + lo][s * 16 + hi * 4];
            dst[0] = cvtpk(e0, e1);
            dst[1] = cvtpk(e2, e3);
        }

        // PV phase: acc[it] (D[p][i]) += El[p][q] * Glt[i][q]
#pragma unroll
        for (int ks = 0; ks < 2; ++ks) {
            const short8 ae = *(const short8*)&El[pw + lo][ks * 32 + hi * 8];
#pragma unroll
            for (int it = 0; it < 4; ++it) {
                const short8 bg = *(const short8*)&Glt[it * 16 + lo][ks * 32 + hi * 8];
                acc[it] = MFMA_B16(ae, bg, acc[it], 0, 0, 0);
            }
        }
    }

    // Part[n,qsp][i][p] fp16
    half_t* Pn = Part + ((size_t)n * QS2 + qsp) * (size_t)NCH * HW;
#pragma unroll
    for (int it = 0; it < 4; ++it) {
        half4v h;
        h[0] = (half_t)acc[it][0]; h[1] = (half_t)acc[it][1];
        h[2] = (half_t)acc[it][2]; h[3] = (half_t)acc[it][3];
        *(half4v*)&Pn[(size_t)(it * 16 + lo) * HW + pblk + pw + hi * 4] = h;
    }
    zl += __shfl_xor(zl, 16, 64);
    zl += __shfl_xor(zl, 32, 64);
    if (lane < 16)
        Zpart[((size_t)n * QS2 + qsp) * HW + pblk + pw + lane] = zl;
}

// ---- K3r: reduce q-slices (fp16 parts), divide by Z -> OutPre[n][i][p] ---------
__global__ __launch_bounds__(256) void k3r_reduce(
    const half_t* __restrict__ Part, const float* __restrict__ Zpart,
    float* __restrict__ OutPre)
{
    const int t  = threadIdx.x;
    const int p2 = blockIdx.x * 256 + t;       // pair index
    const int i0 = blockIdx.y * 8;
    const int n  = blockIdx.z;
    if (p2 >= HW / 2) return;
    const int p = p2 * 2;

    f32x2 z = {0.f, 0.f};
#pragma unroll
    for (int qs = 0; qs < QS2; ++qs) {
        f32x2 zv = *(const f32x2*)&Zpart[((size_t)n * QS2 + qs) * HW + p];
        z += zv;
    }
    const float zix = 1.f / z[0], ziy = 1.f / z[1];

    float* On = OutPre + (size_t)n * NCH * HW;
#pragma unroll
    for (int j = 0; j < 8; ++j) {
        const int i = i0 + j;
        float sx = 0.f, sy = 0.f;
#pragma unroll
        for (int qs = 0; qs < QS2; ++qs) {
            half2v h = *(const half2v*)&Part[(((size_t)n * QS2 + qs) * NCH + i) * HW + p];
            sx += (float)h[0];
            sy += (float)h[1];
        }
        f32x2 o = {sx * zix, sy * ziy};
        *(f32x2*)&On[(size_t)i * HW + p] = o;
    }
}

// ---- K4: depthwise 3x3 (pad 1) + BN2 + residual -> fp32 out --------------------
__global__ __launch_bounds__(256) void k4_dwconv(
    const float* __restrict__ OutPre, const float* __restrict__ l,
    const float* __restrict__ wdw,
    const float* __restrict__ gamma, const float* __restrict__ beta,
    const float* __restrict__ mean, const float* __restrict__ var,
    float* __restrict__ out)
{
    const size_t e = (size_t)blockIdx.x * 256 + threadIdx.x;
    const int p = (int)(e % HW);
    const int i = (int)((e / HW) % NCH);
    const int y = p / 56, x = p % 56;
    const float* src = OutPre + (e - p);

    float acc = 0.f;
#pragma unroll
    for (int dy = -1; dy <= 1; ++dy) {
        int yy = y + dy;
        if (yy < 0 || yy >= 56) continue;
#pragma unroll
        for (int dx = -1; dx <= 1; ++dx) {
            int xx = x + dx;
            if (xx < 0 || xx >= 56) continue;
            acc += wdw[i * 9 + (dy + 1) * 3 + (dx + 1)] * src[yy * 56 + xx];
        }
    }
    const float sc = rsqrtf(var[i] + EPSV) * gamma[i];
    float yv = (acc - mean[i]) * sc + beta[i];
    yv += l[e];
    out[e] = yv;
}

// -------------------------------------------------------------------------------
extern "C" void kernel_launch(void* const* d_in, const int* in_sizes, int n_in,
                              void* d_out, int out_size, void* d_ws, size_t ws_size,
                              hipStream_t stream)
{
    const float* l      = (const float*)d_in[0];
    const float* w_in   = (const float*)d_in[1];
    const float* gamma1 = (const float*)d_in[2];
    const float* beta1  = (const float*)d_in[3];
    const float* mean1  = (const float*)d_in[4];
    const float* var1   = (const float*)d_in[5];
    const float* w_dw   = (const float*)d_in[6];
    const float* gamma2 = (const float*)d_in[7];
    const float* beta2  = (const float*)d_in[8];
    const float* mean2  = (const float*)d_in[9];
    const float* var2   = (const float*)d_in[10];
    float* out = (float*)d_out;

    char* ws = (char*)d_ws;
    const size_t szTheta = (size_t)NB * HW * CRED * 2;        // 1.6 MB
    const size_t szGbt   = (size_t)NB * NCH * HW * 2;         // 3.2 MB
    const size_t szOut   = (size_t)NB * NCH * HW * 4;         // 6.4 MB
    const size_t szCrow  = (size_t)NB * HW * 4;               // 100 KB
    const size_t szZpt   = (size_t)QS2 * NB * HW * 4;         // 0.7 MB
    const size_t szZp    = (size_t)NB * QS2 * HW * 4;         // 0.7 MB

    unsigned short* theta_bf = (unsigned short*)ws;
    unsigned short* Gbt      = (unsigned short*)(ws + szTheta);
    float* OutPre = (float*)(ws + szTheta + szGbt);
    float* crow   = (float*)(ws + szTheta + szGbt + szOut);
    float* zpart  = (float*)(ws + szTheta + szGbt + szOut + szCrow);
    float* Zp     = (float*)(ws + szTheta + szGbt + szOut + szCrow + szZpt);
    half_t* Part  = (half_t*)(ws + szTheta + szGbt + szOut + szCrow + szZpt + szZp);
    (void)ws_size;

    k1_conv1x1<<<dim3(HW / 64, NB), 256, 0, stream>>>(
        l, w_in, gamma1, beta1, mean1, var1, theta_bf, Gbt);

    k2s_stats<<<dim3(HW / 64, QS2, NB), 256, 0, stream>>>(theta_bf, zpart);

    k2c_combine<<<dim3((NB * HW) / 256), 256, 0, stream>>>(zpart, crow);

    k3f_fused<<<dim3(HW / 64, QS2, NB), 256, 0, stream>>>(
        theta_bf, Gbt, crow, Part, Zp);

    k3r_reduce<<<dim3((HW / 2 + 255) / 256, NCH / 8, NB), 256, 0, stream>>>(
        Part, Zp, OutPre);

    k4_dwconv<<<dim3((NB * NCH * HW) / 256), 256, 0, stream>>>(
        OutPre, l, w_dw, gamma2, beta2, mean2, var2, out);
}

// Round 11
// 102.746 us; speedup vs baseline: 11.6013x; 1.0236x over previous
//
#include <hip/hip_runtime.h>

#define HW   3136
#define NCH  64
#define CRED 32
#define NB   8
#define EPSV 1e-5f
#define QS2  7

// sqrt(log2(e)) — both theta operands scaled => S' = S * log2(e)
#define SQRT_L2E 1.2011224087f
// log2(log2(e))
#define LOG2_L2E 0.5287663729f

typedef __attribute__((ext_vector_type(8))) short short8;
typedef __attribute__((ext_vector_type(4))) float f32x4;
typedef __attribute__((ext_vector_type(2))) float f32x2;
typedef _Float16 half_t;
typedef __attribute__((ext_vector_type(2))) _Float16 half2v;
typedef __attribute__((ext_vector_type(4))) _Float16 half4v;

#define MFMA_B16 __builtin_amdgcn_mfma_f32_16x16x32_bf16

__device__ __forceinline__ unsigned short f2b(float x) {
    union { float f; unsigned u; } v; v.f = x;
    unsigned r = v.u + 0x7fff + ((v.u >> 16) & 1);
    return (unsigned short)(r >> 16);
}

// raw v_exp_f32: 2^x
__device__ __forceinline__ float ex2(float x) {
#if __has_builtin(__builtin_amdgcn_exp2f)
    return __builtin_amdgcn_exp2f(x);
#else
    float r;
    asm volatile("v_exp_f32 %0, %1" : "=v"(r) : "v"(x));
    return r;
#endif
}

// pack two f32 -> bf16x2 in one instruction
__device__ __forceinline__ unsigned cvtpk(float a, float b) {
    unsigned r;
    asm("v_cvt_pk_bf16_f32 %0, %1, %2" : "=v"(r) : "v"(a), "v"(b));
    return r;
}

// ---- K1: conv1x1 + BN1 + ReLU6 -> Gbt[n][i][p] bf16; theta_bf[n][p][c] scaled --
__global__ __launch_bounds__(256) void k1_conv1x1(
    const float* __restrict__ l, const float* __restrict__ w,
    const float* __restrict__ gamma, const float* __restrict__ beta,
    const float* __restrict__ mean, const float* __restrict__ var,
    unsigned short* __restrict__ theta_bf, unsigned short* __restrict__ Gbt)
{
    __shared__ float Wt[NCH][65];   // Wt[c][i]; reused as G-transpose [i][p]
    __shared__ float Lt[NCH][65];   // Lt[c][j]
    const int t  = threadIdx.x;
    const int n  = blockIdx.y;
    const int p0 = blockIdx.x * 64;

    for (int idx = t; idx < NCH * 64; idx += 256) {
        int c = idx >> 6, j = idx & 63;
        Wt[c][j] = w[j * NCH + c];
        Lt[c][j] = l[((size_t)n * NCH + c) * HW + p0 + j];
    }
    __syncthreads();

    // emit theta_bf[n][p0+p][c0..c0+7], pre-scaled by sqrt(log2 e)
    {
        const int p = t >> 2, c0 = (t & 3) * 8;
        unsigned short pk[8];
#pragma unroll
        for (int j = 0; j < 8; ++j) pk[j] = f2b(Lt[c0 + j][p] * SQRT_L2E);
        *(short8*)&theta_bf[((size_t)n * HW + p0 + p) * CRED + c0] = *(short8*)pk;
    }

    const int i   = t & 63;
    const int pj0 = t >> 6;
    const float mu = mean[i];
    const float sc = rsqrtf(var[i] + EPSV) * gamma[i];
    const float bi = beta[i];

    float acc[16];
#pragma unroll
    for (int k = 0; k < 16; ++k) acc[k] = 0.f;
#pragma unroll
    for (int c = 0; c < NCH; ++c) {
        float wci = Wt[c][i];
#pragma unroll
        for (int k = 0; k < 16; ++k) acc[k] += wci * Lt[c][pj0 + 4 * k];
    }
    __syncthreads();   // all reads of Wt done before reuse

#pragma unroll
    for (int k = 0; k < 16; ++k) {
        float y = (acc[k] - mu) * sc + bi;
        y = fminf(fmaxf(y, 0.f), 6.f);
        Wt[i][pj0 + 4 * k] = y;        // transpose buffer [i][p]
    }
    __syncthreads();

    {
        const int ir = t >> 2, pc = (t & 3) * 16;
        unsigned short pk[16];
#pragma unroll
        for (int j = 0; j < 16; ++j) pk[j] = f2b(Wt[ir][pc + j]);
        unsigned short* dst = &Gbt[((size_t)n * NCH + ir) * HW + p0 + pc];
        *(short8*)&dst[0] = *(short8*)&pk[0];
        *(short8*)&dst[8] = *(short8*)&pk[8];
    }
}

// ---- K2s (MFMA, no LDS): zpart[psp][n][q] = sum_{p in split} 2^(S'[q,p]) -------
// No LDS, no barriers: register prefetch of the next pt's B-fragments is
// unconditionally safe here (pure global->reg loads, clamped index, no sync).
__global__ __launch_bounds__(256) void k2s_stats(
    const unsigned short* __restrict__ theta_bf, float* __restrict__ zpart)
{
    const int t = threadIdx.x, w = t >> 6, lane = t & 63;
    const int lo = lane & 15, hi = lane >> 4;
    const int n = blockIdx.z, psp = blockIdx.y;
    const int q0 = blockIdx.x * 64;

    const unsigned short* thn = theta_bf + (size_t)n * HW * CRED;

    const short8 afrag = *(const short8*)&thn[(q0 + w * 16 + lo) * CRED + hi * 8];

    float z[4] = {0.f, 0.f, 0.f, 0.f};

    short8 bf[4];
    {
        const int p0 = psp * 448;
#pragma unroll
        for (int ss = 0; ss < 4; ++ss)
            bf[ss] = *(const short8*)&thn[(p0 + ss * 16 + lo) * CRED + hi * 8];
    }

    for (int pt = 0; pt < 7; ++pt) {
        // prefetch pt+1 fragments (clamped: pt=6 redundantly reloads pt=6, L1-hit)
        const int pn = psp * 448 + ((pt < 6) ? (pt + 1) * 64 : 6 * 64);
        short8 nf[4];
#pragma unroll
        for (int ss = 0; ss < 4; ++ss)
            nf[ss] = *(const short8*)&thn[(pn + ss * 16 + lo) * CRED + hi * 8];

#pragma unroll
        for (int ss = 0; ss < 4; ++ss) {
            f32x4 zero = {0.f, 0.f, 0.f, 0.f};
            f32x4 d = MFMA_B16(afrag, bf[ss], zero, 0, 0, 0);
#pragma unroll
            for (int r = 0; r < 4; ++r) z[r] += ex2(d[r]);
        }

#pragma unroll
        for (int ss = 0; ss < 4; ++ss) bf[ss] = nf[ss];
    }

#pragma unroll
    for (int r = 0; r < 4; ++r) {
        float v = z[r];
        v += __shfl_xor(v, 1, 64);
        v += __shfl_xor(v, 2, 64);
        v += __shfl_xor(v, 4, 64);
        v += __shfl_xor(v, 8, 64);
        z[r] = v;
    }
    if (lo == 0) {
        f32x4 st = {z[0], z[1], z[2], z[3]};
        *(f32x4*)&zpart[((size_t)psp * NB + n) * HW + q0 + w * 16 + hi * 4] = st;
    }
}

// ---- K2c: crow[n][q] = log2(log2 e) - log2(sum_psp zpart) ----------------------
__global__ __launch_bounds__(256) void k2c_combine(
    const float* __restrict__ zpart, float* __restrict__ crow)
{
    const int idx = blockIdx.x * 256 + threadIdx.x;
    float s = 0.f;
#pragma unroll
    for (int ps = 0; ps < QS2; ++ps) s += zpart[(size_t)ps * NB * HW + idx];
    crow[idx] = LOG2_L2E - __log2f(s);
}

// ---- K3f (MFMA): d = S' + crow (C-op); E = 2^(2^d); PV over q-slice ------------
// Round-6-VERIFIED sync skeleton (2 barriers/tile, single Glt buffer, El
// write->read wave-private with no barrier between). Only change: the current
// tile's aq/crow loads are issued in the staging region (between the barriers)
// so they drain at the barrier's implicit vmcnt(0) — the S phase then has zero
// exposed global latency. No value lives across iterations; no new races.
__global__ __launch_bounds__(256) void k3f_fused(
    const unsigned short* __restrict__ theta_bf,
    const unsigned short* __restrict__ Gbt,
    const float* __restrict__ crow,
    half_t* __restrict__ Part, float* __restrict__ Zpart)
{
    __shared__ unsigned short Glt[64][76];   // G^T [i][q], pad 76
    __shared__ unsigned short El[64][76];    // E   [p][q] (wave-private rows)

    const int t = threadIdx.x, w = t >> 6, lane = t & 63;
    const int lo = lane & 15, hi = lane >> 4;
    const int n = blockIdx.z, qsp = blockIdx.y;
    const int pblk = blockIdx.x * 64;
    const int pw = w * 16;

    const unsigned short* thn = theta_bf + (size_t)n * HW * CRED;
    const float* crn = crow + (size_t)n * HW;

    // block-invariant theta_p fragment, direct from global
    const short8 bp = *(const short8*)&thn[(pblk + pw + lo) * CRED + hi * 8];

    f32x4 acc[4];
#pragma unroll
    for (int it = 0; it < 4; ++it) acc[it] = (f32x4){0.f, 0.f, 0.f, 0.f};
    float zl = 0.f;

    for (int tile = 0; tile < 7; ++tile) {
        const int qb = qsp * 448 + tile * 64;
        __syncthreads();
        // stage G^T tile: pure bf16 row copy
        {
            const int ir = t >> 2, qoff = (t & 3) * 16;
            const unsigned short* src = &Gbt[((size_t)n * NCH + ir) * HW + qb + qoff];
            *(short8*)&Glt[ir][qoff]     = *(const short8*)&src[0];
            *(short8*)&Glt[ir][qoff + 8] = *(const short8*)&src[8];
        }
        // issue this tile's aq/crow loads here: they complete by the barrier's
        // implicit vmcnt(0) drain, making the S phase pure compute.
        short8 aqr[4];
        f32x4  cvr[4];
#pragma unroll
        for (int s = 0; s < 4; ++s) {
            aqr[s] = *(const short8*)&thn[(qb + s * 16 + lo) * CRED + hi * 8];
            cvr[s] = *(const f32x4*)&crn[qb + s * 16 + hi * 4];
        }
        __syncthreads();

        // S phase: 4 q-subtiles; E rows -> El[p][q]
#pragma unroll
        for (int s = 0; s < 4; ++s) {
            f32x4 d = MFMA_B16(aqr[s], bp, cvr[s], 0, 0, 0);
            float e0 = ex2(ex2(d[0]));
            float e1 = ex2(ex2(d[1]));
            float e2 = ex2(ex2(d[2]));
            float e3 = ex2(ex2(d[3]));
            zl += (e0 + e1) + (e2 + e3);
            unsigned* dst = (unsigned*)&El[pw + lo][s * 16 + hi * 4];
            dst[0] = cvtpk(e0, e1);
            dst[1] = cvtpk(e2, e3);
        }

        // PV phase: acc[it] (D[p][i]) += El[p][q] * Glt[i][q]
#pragma unroll
        for (int ks = 0; ks < 2; ++ks) {
            const short8 ae = *(const short8*)&El[pw + lo][ks * 32 + hi * 8];
#pragma unroll
            for (int it = 0; it < 4; ++it) {
                const short8 bg = *(const short8*)&Glt[it * 16 + lo][ks * 32 + hi * 8];
                acc[it] = MFMA_B16(ae, bg, acc[it], 0, 0, 0);
            }
        }
    }

    // Part[n,qsp][i][p] fp16
    half_t* Pn = Part + ((size_t)n * QS2 + qsp) * (size_t)NCH * HW;
#pragma unroll
    for (int it = 0; it < 4; ++it) {
        half4v h;
        h[0] = (half_t)acc[it][0]; h[1] = (half_t)acc[it][1];
        h[2] = (half_t)acc[it][2]; h[3] = (half_t)acc[it][3];
        *(half4v*)&Pn[(size_t)(it * 16 + lo) * HW + pblk + pw + hi * 4] = h;
    }
    zl += __shfl_xor(zl, 16, 64);
    zl += __shfl_xor(zl, 32, 64);
    if (lane < 16)
        Zpart[((size_t)n * QS2 + qsp) * HW + pblk + pw + lane] = zl;
}

// ---- K3r: reduce q-slices (fp16 parts), divide by Z -> OutPre[n][i][p] ---------
__global__ __launch_bounds__(256) void k3r_reduce(
    const half_t* __restrict__ Part, const float* __restrict__ Zpart,
    float* __restrict__ OutPre)
{
    const int t  = threadIdx.x;
    const int p2 = blockIdx.x * 256 + t;       // pair index
    const int i0 = blockIdx.y * 8;
    const int n  = blockIdx.z;
    if (p2 >= HW / 2) return;
    const int p = p2 * 2;

    f32x2 z = {0.f, 0.f};
#pragma unroll
    for (int qs = 0; qs < QS2; ++qs) {
        f32x2 zv = *(const f32x2*)&Zpart[((size_t)n * QS2 + qs) * HW + p];
        z += zv;
    }
    const float zix = 1.f / z[0], ziy = 1.f / z[1];

    float* On = OutPre + (size_t)n * NCH * HW;
#pragma unroll
    for (int j = 0; j < 8; ++j) {
        const int i = i0 + j;
        float sx = 0.f, sy = 0.f;
#pragma unroll
        for (int qs = 0; qs < QS2; ++qs) {
            half2v h = *(const half2v*)&Part[(((size_t)n * QS2 + qs) * NCH + i) * HW + p];
            sx += (float)h[0];
            sy += (float)h[1];
        }
        f32x2 o = {sx * zix, sy * ziy};
        *(f32x2*)&On[(size_t)i * HW + p] = o;
    }
}

// ---- K4: depthwise 3x3 (pad 1) + BN2 + residual -> fp32 out --------------------
__global__ __launch_bounds__(256) void k4_dwconv(
    const float* __restrict__ OutPre, const float* __restrict__ l,
    const float* __restrict__ wdw,
    const float* __restrict__ gamma, const float* __restrict__ beta,
    const float* __restrict__ mean, const float* __restrict__ var,
    float* __restrict__ out)
{
    const size_t e = (size_t)blockIdx.x * 256 + threadIdx.x;
    const int p = (int)(e % HW);
    const int i = (int)((e / HW) % NCH);
    const int y = p / 56, x = p % 56;
    const float* src = OutPre + (e - p);

    float acc = 0.f;
#pragma unroll
    for (int dy = -1; dy <= 1; ++dy) {
        int yy = y + dy;
        if (yy < 0 || yy >= 56) continue;
#pragma unroll
        for (int dx = -1; dx <= 1; ++dx) {
            int xx = x + dx;
            if (xx < 0 || xx >= 56) continue;
            acc += wdw[i * 9 + (dy + 1) * 3 + (dx + 1)] * src[yy * 56 + xx];
        }
    }
    const float sc = rsqrtf(var[i] + EPSV) * gamma[i];
    float yv = (acc - mean[i]) * sc + beta[i];
    yv += l[e];
    out[e] = yv;
}

// -------------------------------------------------------------------------------
extern "C" void kernel_launch(void* const* d_in, const int* in_sizes, int n_in,
                              void* d_out, int out_size, void* d_ws, size_t ws_size,
                              hipStream_t stream)
{
    const float* l      = (const float*)d_in[0];
    const float* w_in   = (const float*)d_in[1];
    const float* gamma1 = (const float*)d_in[2];
    const float* beta1  = (const float*)d_in[3];
    const float* mean1  = (const float*)d_in[4];
    const float* var1   = (const float*)d_in[5];
    const float* w_dw   = (const float*)d_in[6];
    const float* gamma2 = (const float*)d_in[7];
    const float* beta2  = (const float*)d_in[8];
    const float* mean2  = (const float*)d_in[9];
    const float* var2   = (const float*)d_in[10];
    float* out = (float*)d_out;

    char* ws = (char*)d_ws;
    const size_t szTheta = (size_t)NB * HW * CRED * 2;        // 1.6 MB
    const size_t szGbt   = (size_t)NB * NCH * HW * 2;         // 3.2 MB
    const size_t szOut   = (size_t)NB * NCH * HW * 4;         // 6.4 MB
    const size_t szCrow  = (size_t)NB * HW * 4;               // 100 KB
    const size_t szZpt   = (size_t)QS2 * NB * HW * 4;         // 0.7 MB
    const size_t szZp    = (size_t)NB * QS2 * HW * 4;         // 0.7 MB

    unsigned short* theta_bf = (unsigned short*)ws;
    unsigned short* Gbt      = (unsigned short*)(ws + szTheta);
    float* OutPre = (float*)(ws + szTheta + szGbt);
    float* crow   = (float*)(ws + szTheta + szGbt + szOut);
    float* zpart  = (float*)(ws + szTheta + szGbt + szOut + szCrow);
    float* Zp     = (float*)(ws + szTheta + szGbt + szOut + szCrow + szZpt);
    half_t* Part  = (half_t*)(ws + szTheta + szGbt + szOut + szCrow + szZpt + szZp);
    (void)ws_size;

    k1_conv1x1<<<dim3(HW / 64, NB), 256, 0, stream>>>(
        l, w_in, gamma1, beta1, mean1, var1, theta_bf, Gbt);

    k2s_stats<<<dim3(HW / 64, QS2, NB), 256, 0, stream>>>(theta_bf, zpart);

    k2c_combine<<<dim3((NB * HW) / 256), 256, 0, stream>>>(zpart, crow);

    k3f_fused<<<dim3(HW / 64, QS2, NB), 256, 0, stream>>>(
        theta_bf, Gbt, crow, Part, Zp);

    k3r_reduce<<<dim3((HW / 2 + 255) / 256, NCH / 8, NB), 256, 0, stream>>>(
        Part, Zp, OutPre);

    k4_dwconv<<<dim3((NB * NCH * HW) / 256), 256, 0, stream>>>(
        OutPre, l, w_dw, gamma2, beta2, mean2, var2, out);
}